// Round 1
// baseline (268.428 us; speedup 1.0000x reference)
//
#include <hip/hip_runtime.h>
#include <cstdint>
#include <cstddef>

// ---------- types ----------
typedef __bf16 bf16_t;
typedef __bf16 bf16x8 __attribute__((ext_vector_type(8)));
typedef __bf16 bf16x4 __attribute__((ext_vector_type(4)));
typedef float  f32x4  __attribute__((ext_vector_type(4)));

#define MFMA_BF16(a, b, c) __builtin_amdgcn_mfma_f32_16x16x32_bf16((a), (b), (c), 0, 0, 0)

// async global->LDS, 16B per lane. LDS dest must be wave-uniform base + lane*16.
__device__ __forceinline__ void async_load16(const void* g, void* l) {
    __builtin_amdgcn_global_load_lds((const __attribute__((address_space(1))) void*)g,
                                     (__attribute__((address_space(3))) void*)l,
                                     16, 0, 0);
}

// ---------- problem constants ----------
#define Bq   2
#define Tq   2048
#define Cq   1024
#define Hq   16
#define HSq  64
#define LDQKV 3072   // 3*C
#define Mrows 4096   // B*T

// ---------- fp32 -> bf16 convert ----------
__global__ void cvt_f32_bf16(const float* __restrict__ in, bf16_t* __restrict__ out, int n) {
    int i = (blockIdx.x * blockDim.x + threadIdx.x) * 4;
    if (i + 3 < n) {
        float4 v = *(const float4*)(in + i);
        bf16x4 o;
        o[0] = (bf16_t)v.x; o[1] = (bf16_t)v.y; o[2] = (bf16_t)v.z; o[3] = (bf16_t)v.w;
        *(bf16x4*)(out + i) = o;
    }
}

// ---------- GEMM: C[m][n] = sum_k A[m][k]*B[n][k] (+bias), A:[M,K], B:[N,K] row-major ----------
// 128x128 tile, BK=32, 256 threads = 4 waves (2x2 of 64x64), 4x4 16x16x32 MFMA per wave.
template <int OUT_FP32>
__global__ __launch_bounds__(256)
void gemm_bt(const bf16_t* __restrict__ A, const bf16_t* __restrict__ B,
             void* __restrict__ Cout, const float* __restrict__ bias,
             int M, int N, int K) {
    __shared__ __align__(16) bf16_t As[128 * 32];
    __shared__ __align__(16) bf16_t Bs[128 * 32];

    const int tid  = threadIdx.x;
    const int wave = tid >> 6;
    const int lane = tid & 63;
    const int m0 = blockIdx.y * 128;
    const int n0 = blockIdx.x * 128;
    const int wm = (wave >> 1) * 64;
    const int wn = (wave & 1) * 64;
    const int lrow = lane & 15;
    const int lko  = (lane >> 4) * 8;

    f32x4 acc[4][4] = {};

    const bf16_t* Ag = A + (size_t)m0 * K;
    const bf16_t* Bg = B + (size_t)n0 * K;
    const int c0 = tid, c1 = tid + 256;

    for (int k0 = 0; k0 < K; k0 += 32) {
        // stage A,B tiles: chunk c -> row c>>2, kcols (c&3)*8..+7, LDS offset c*16B
        async_load16(Ag + (size_t)(c0 >> 2) * K + k0 + (c0 & 3) * 8, &As[c0 * 8]);
        async_load16(Ag + (size_t)(c1 >> 2) * K + k0 + (c1 & 3) * 8, &As[c1 * 8]);
        async_load16(Bg + (size_t)(c0 >> 2) * K + k0 + (c0 & 3) * 8, &Bs[c0 * 8]);
        async_load16(Bg + (size_t)(c1 >> 2) * K + k0 + (c1 & 3) * 8, &Bs[c1 * 8]);
        __syncthreads();

        bf16x8 af[4], bf[4];
        #pragma unroll
        for (int r = 0; r < 4; r++) af[r] = *(const bf16x8*)&As[(wm + r * 16 + lrow) * 32 + lko];
        #pragma unroll
        for (int c = 0; c < 4; c++) bf[c] = *(const bf16x8*)&Bs[(wn + c * 16 + lrow) * 32 + lko];
        #pragma unroll
        for (int r = 0; r < 4; r++)
            #pragma unroll
            for (int c = 0; c < 4; c++)
                acc[r][c] = MFMA_BF16(af[r], bf[c], acc[r][c]);
        __syncthreads();
    }

    // epilogue: C/D layout col=lane&15, row=(lane>>4)*4+v
    const int er = (lane >> 4) * 4;
    const int ec = lane & 15;
    #pragma unroll
    for (int r = 0; r < 4; r++) {
        #pragma unroll
        for (int c = 0; c < 4; c++) {
            int m = m0 + wm + r * 16 + er;
            int n = n0 + wn + c * 16 + ec;
            #pragma unroll
            for (int v = 0; v < 4; v++) {
                if (OUT_FP32) {
                    ((float*)Cout)[(size_t)(m + v) * N + n] = acc[r][c][v] + bias[n];
                } else {
                    ((bf16_t*)Cout)[(size_t)(m + v) * N + n] = (bf16_t)acc[r][c][v];
                }
            }
        }
    }
}

// ---------- V transpose: Vt[b][h][d][t] = QKV[b*T+t][2C + h*64 + d] ----------
__global__ __launch_bounds__(256)
void transpose_v(const bf16_t* __restrict__ qkv, bf16_t* __restrict__ vt) {
    __shared__ __align__(16) bf16_t Ls[64 * 72];
    const int tid = threadIdx.x;
    const int t0 = blockIdx.x * 64;
    const int bh = blockIdx.y;
    const int b = bh >> 4, h = bh & 15;
    const bf16_t* src = qkv + (size_t)b * Tq * LDQKV + 2 * Cq + h * HSq;
    #pragma unroll
    for (int i = 0; i < 2; i++) {
        int c = i * 256 + tid;
        int tl = c >> 3, dc = (c & 7) * 8;
        bf16x8 v = *(const bf16x8*)(src + (size_t)(t0 + tl) * LDQKV + dc);
        *(bf16x8*)&Ls[tl * 72 + dc] = v;
    }
    __syncthreads();
    bf16_t* dst = vt + (size_t)bh * HSq * Tq;
    #pragma unroll
    for (int i = 0; i < 2; i++) {
        int c = i * 256 + tid;
        int d = c >> 3, tc = (c & 7) * 8;
        bf16x8 v;
        #pragma unroll
        for (int j = 0; j < 8; j++) v[j] = Ls[(tc + j) * 72 + d];
        *(bf16x8*)&dst[(size_t)d * Tq + t0 + tc] = v;
    }
}

// ---------- attention: per (b,h,q-tile of 64), softplus + causal + online L2 norm ----------
// ao[(b*T+t)][h*64+d] = (sum_k w[t,k] V[k,d]) / sqrt(sum_k w^2)
__global__ __launch_bounds__(256)
void attn_kernel(const bf16_t* __restrict__ qkv, const bf16_t* __restrict__ vt,
                 bf16_t* __restrict__ ao) {
    __shared__ __align__(16) bf16_t Ks[64 * 72];  // [key][d]
    __shared__ __align__(16) bf16_t Vs[64 * 72];  // [d][key]  (from Vt)
    __shared__ __align__(16) bf16_t Ws[64 * 72];  // [q][key]

    const int tid = threadIdx.x;
    const int wave = tid >> 6;
    const int lane = tid & 63;
    const int lrow = lane & 15;
    const int lko  = (lane >> 4) * 8;
    const int er = (lane >> 4) * 4;
    const int ec = lane & 15;

    const int qi = gridDim.x - 1 - blockIdx.x;  // heavy blocks first
    const int q0 = qi * 64;
    const int bh = blockIdx.y;
    const int b = bh >> 4, h = bh & 15;

    const bf16_t* Qb  = qkv + (size_t)b * Tq * LDQKV + h * HSq;
    const bf16_t* Kb  = Qb + Cq;
    const bf16_t* Vtb = vt + (size_t)bh * HSq * Tq;

    // Q fragments (A-operand layout), once per block
    bf16x8 qf[2];
    {
        const bf16_t* qrow = Qb + (size_t)(q0 + wave * 16 + lrow) * LDQKV + lko;
        qf[0] = *(const bf16x8*)(qrow);
        qf[1] = *(const bf16x8*)(qrow + 32);
    }

    f32x4 oacc[4] = {};
    float n2[4] = {0.f, 0.f, 0.f, 0.f};
    const int myq = q0 + wave * 16 + er;

    for (int kt = 0; kt <= qi; kt++) {
        const int key0 = kt * 64;
        // stage K tile [64 key][64 d] and V tile [64 d][64 key] (padded stride 72)
        #pragma unroll
        for (int i = 0; i < 2; i++) {
            int c = i * 256 + tid;
            int r = c >> 3, cc = (c & 7) * 8;
            *(bf16x8*)&Ks[r * 72 + cc] = *(const bf16x8*)(Kb + (size_t)(key0 + r) * LDQKV + cc);
            *(bf16x8*)&Vs[r * 72 + cc] = *(const bf16x8*)(Vtb + (size_t)r * Tq + key0 + cc);
        }
        __syncthreads();

        // S = Q K^T  (4 key-subtiles x 2 k-steps)
        f32x4 sacc[4] = {};
        #pragma unroll
        for (int j = 0; j < 4; j++) {
            bf16x8 kf0 = *(const bf16x8*)&Ks[(j * 16 + lrow) * 72 + lko];
            bf16x8 kf1 = *(const bf16x8*)&Ks[(j * 16 + lrow) * 72 + 32 + lko];
            sacc[j] = MFMA_BF16(qf[0], kf0, sacc[j]);
            sacc[j] = MFMA_BF16(qf[1], kf1, sacc[j]);
        }

        // softplus + causal mask + n2 accum + write W tile (own wave's rows only)
        #pragma unroll
        for (int j = 0; j < 4; j++) {
            #pragma unroll
            for (int v = 0; v < 4; v++) {
                float s = sacc[j][v] * 0.125f;
                float w = fmaxf(s, 0.0f) + __logf(1.0f + __expf(-fabsf(s)));
                int key = key0 + j * 16 + ec;
                if (key > myq + v) w = 0.0f;
                bf16_t wb = (bf16_t)w;
                float wr = (float)wb;
                n2[v] += wr * wr;
                Ws[(wave * 16 + er + v) * 72 + j * 16 + ec] = wb;
            }
        }

        // O += W V  (W in A-layout from LDS, V^T already K-major in Vs)
        #pragma unroll
        for (int s = 0; s < 2; s++) {
            bf16x8 wf = *(const bf16x8*)&Ws[(wave * 16 + lrow) * 72 + s * 32 + lko];
            #pragma unroll
            for (int jd = 0; jd < 4; jd++) {
                bf16x8 vf = *(const bf16x8*)&Vs[(jd * 16 + lrow) * 72 + s * 32 + lko];
                oacc[jd] = MFMA_BF16(wf, vf, oacc[jd]);
            }
        }
        __syncthreads();
    }

    // reduce n2 over the 16 lanes holding the same rows (lane&15 varies)
    #pragma unroll
    for (int v = 0; v < 4; v++) {
        float x = n2[v];
        #pragma unroll
        for (int m = 1; m < 16; m <<= 1) x += __shfl_xor(x, m, 64);
        n2[v] = x;
    }
    float inv[4];
    #pragma unroll
    for (int v = 0; v < 4; v++) inv[v] = rsqrtf(n2[v]);

    bf16_t* aob = ao + (size_t)(b * Tq + q0 + wave * 16 + er) * Cq + h * HSq;
    #pragma unroll
    for (int jd = 0; jd < 4; jd++) {
        #pragma unroll
        for (int v = 0; v < 4; v++) {
            aob[(size_t)v * Cq + jd * 16 + ec] = (bf16_t)(oacc[jd][v] * inv[v]);
        }
    }
}

// ---------- launch ----------
extern "C" void kernel_launch(void* const* d_in, const int* in_sizes, int n_in,
                              void* d_out, int out_size, void* d_ws, size_t ws_size,
                              hipStream_t stream) {
    const float* x     = (const float*)d_in[0];
    const float* wqkv  = (const float*)d_in[1];
    const float* wproj = (const float*)d_in[2];
    const float* bproj = (const float*)d_in[3];
    float* out = (float*)d_out;

    char* ws = (char*)d_ws;
    bf16_t* xb     = (bf16_t*)(ws);                      //  8 MB  [4096,1024]
    bf16_t* wqkvb  = (bf16_t*)(ws + ( 8u << 20));        //  6 MB  [3072,1024]
    bf16_t* wprojb = (bf16_t*)(ws + (14u << 20));        //  2 MB  [1024,1024]
    bf16_t* qkvb   = (bf16_t*)(ws + (16u << 20));        // 24 MB  [4096,3072]
    bf16_t* vtb    = (bf16_t*)(ws + (40u << 20));        //  8 MB  [32,64,2048]
    bf16_t* aob    = (bf16_t*)(ws + (48u << 20));        //  8 MB  [4096,1024]

    cvt_f32_bf16<<<4096, 256, 0, stream>>>(x, xb, Mrows * Cq);
    cvt_f32_bf16<<<3072, 256, 0, stream>>>(wqkv, wqkvb, 3 * Cq * Cq);
    cvt_f32_bf16<<<1024, 256, 0, stream>>>(wproj, wprojb, Cq * Cq);

    // QKV projection: [4096,1024] x [3072,1024]^T -> bf16 [4096,3072]
    gemm_bt<0><<<dim3(24, 32), 256, 0, stream>>>(xb, wqkvb, (void*)qkvb, nullptr,
                                                 Mrows, 3 * Cq, Cq);
    // V transpose for PV B-operand
    transpose_v<<<dim3(32, 32), 256, 0, stream>>>(qkvb, vtb);
    // attention
    attn_kernel<<<dim3(32, 32), 256, 0, stream>>>(qkvb, vtb, aob);
    // output projection + bias: [4096,1024] x [1024,1024]^T -> fp32 [4096,1024]
    gemm_bt<1><<<dim3(8, 32), 256, 0, stream>>>(aob, wprojb, (void*)out, bproj,
                                                Mrows, Cq, Cq);
}

// Round 2
// 234.834 us; speedup vs baseline: 1.1431x; 1.1431x over previous
//
#include <hip/hip_runtime.h>
#include <cstdint>
#include <cstddef>

// ---------- types ----------
typedef __bf16 bf16_t;
typedef __bf16 bf16x8 __attribute__((ext_vector_type(8)));
typedef __bf16 bf16x4 __attribute__((ext_vector_type(4)));
typedef float  f32x4  __attribute__((ext_vector_type(4)));

#define MFMA_BF16(a, b, c) __builtin_amdgcn_mfma_f32_16x16x32_bf16((a), (b), (c), 0, 0, 0)

// async global->LDS, 16B per lane. LDS dest must be wave-uniform base + lane*16.
__device__ __forceinline__ void async_load16(const void* g, void* l) {
    __builtin_amdgcn_global_load_lds((const __attribute__((address_space(1))) void*)g,
                                     (__attribute__((address_space(3))) void*)l,
                                     16, 0, 0);
}

// XOR-swizzled LDS layout for a 64x64 bf16 tile stored as 16B chunks (8 chunks/row).
// chunk (r, cg) lives at slot r*8 + (cg ^ (r&7)); returns bf16 element offset.
#define SWZ(r, cg) ((((r) << 3) | ((cg) ^ ((r) & 7))) << 3)

// ---------- problem constants ----------
#define Bq   2
#define Tq   2048
#define Cq   1024
#define Hq   16
#define HSq  64
#define LDQKV 3072   // 3*C
#define Mrows 4096   // B*T

// ---------- fp32 -> bf16 convert ----------
__global__ void cvt_f32_bf16(const float* __restrict__ in, bf16_t* __restrict__ out, int n) {
    int i = (blockIdx.x * blockDim.x + threadIdx.x) * 4;
    if (i + 3 < n) {
        float4 v = *(const float4*)(in + i);
        bf16x4 o;
        o[0] = (bf16_t)v.x; o[1] = (bf16_t)v.y; o[2] = (bf16_t)v.z; o[3] = (bf16_t)v.w;
        *(bf16x4*)(out + i) = o;
    }
}

// ---------- GEMM: C[m][n] = sum_k A[m][k]*B[n][k] (+bias), A:[M,K], B:[N,K] row-major ----------
template <int OUT_FP32>
__global__ __launch_bounds__(256)
void gemm_bt(const bf16_t* __restrict__ A, const bf16_t* __restrict__ B,
             void* __restrict__ Cout, const float* __restrict__ bias,
             int M, int N, int K) {
    __shared__ __align__(16) bf16_t As[128 * 32];
    __shared__ __align__(16) bf16_t Bs[128 * 32];

    const int tid  = threadIdx.x;
    const int wave = tid >> 6;
    const int lane = tid & 63;
    const int m0 = blockIdx.y * 128;
    const int n0 = blockIdx.x * 128;
    const int wm = (wave >> 1) * 64;
    const int wn = (wave & 1) * 64;
    const int lrow = lane & 15;
    const int lko  = (lane >> 4) * 8;

    f32x4 acc[4][4] = {};

    const bf16_t* Ag = A + (size_t)m0 * K;
    const bf16_t* Bg = B + (size_t)n0 * K;
    const int c0 = tid, c1 = tid + 256;

    for (int k0 = 0; k0 < K; k0 += 32) {
        async_load16(Ag + (size_t)(c0 >> 2) * K + k0 + (c0 & 3) * 8, &As[c0 * 8]);
        async_load16(Ag + (size_t)(c1 >> 2) * K + k0 + (c1 & 3) * 8, &As[c1 * 8]);
        async_load16(Bg + (size_t)(c0 >> 2) * K + k0 + (c0 & 3) * 8, &Bs[c0 * 8]);
        async_load16(Bg + (size_t)(c1 >> 2) * K + k0 + (c1 & 3) * 8, &Bs[c1 * 8]);
        __syncthreads();

        bf16x8 af[4], bfr[4];
        #pragma unroll
        for (int r = 0; r < 4; r++) af[r] = *(const bf16x8*)&As[(wm + r * 16 + lrow) * 32 + lko];
        #pragma unroll
        for (int c = 0; c < 4; c++) bfr[c] = *(const bf16x8*)&Bs[(wn + c * 16 + lrow) * 32 + lko];
        #pragma unroll
        for (int r = 0; r < 4; r++)
            #pragma unroll
            for (int c = 0; c < 4; c++)
                acc[r][c] = MFMA_BF16(af[r], bfr[c], acc[r][c]);
        __syncthreads();
    }

    const int er = (lane >> 4) * 4;
    const int ec = lane & 15;
    #pragma unroll
    for (int r = 0; r < 4; r++) {
        #pragma unroll
        for (int c = 0; c < 4; c++) {
            int m = m0 + wm + r * 16 + er;
            int n = n0 + wn + c * 16 + ec;
            #pragma unroll
            for (int v = 0; v < 4; v++) {
                if (OUT_FP32) {
                    ((float*)Cout)[(size_t)(m + v) * N + n] = acc[r][c][v] + bias[n];
                } else {
                    ((bf16_t*)Cout)[(size_t)(m + v) * N + n] = (bf16_t)acc[r][c][v];
                }
            }
        }
    }
}

// ---------- V transpose: Vt[b][h][d][t] = QKV[b*T+t][2C + h*64 + d] ----------
__global__ __launch_bounds__(256)
void transpose_v(const bf16_t* __restrict__ qkv, bf16_t* __restrict__ vt) {
    __shared__ __align__(16) bf16_t Ls[64 * 72];
    const int tid = threadIdx.x;
    const int t0 = blockIdx.x * 64;
    const int bh = blockIdx.y;
    const int b = bh >> 4, h = bh & 15;
    const bf16_t* src = qkv + (size_t)b * Tq * LDQKV + 2 * Cq + h * HSq;
    #pragma unroll
    for (int i = 0; i < 2; i++) {
        int c = i * 256 + tid;
        int tl = c >> 3, dc = (c & 7) * 8;
        bf16x8 v = *(const bf16x8*)(src + (size_t)(t0 + tl) * LDQKV + dc);
        *(bf16x8*)&Ls[tl * 72 + dc] = v;
    }
    __syncthreads();
    bf16_t* dst = vt + (size_t)bh * HSq * Tq;
    #pragma unroll
    for (int i = 0; i < 2; i++) {
        int c = i * 256 + tid;
        int d = c >> 3, tc = (c & 7) * 8;
        bf16x8 v;
        #pragma unroll
        for (int j = 0; j < 8; j++) v[j] = Ls[(tc + j) * 72 + d];
        *(bf16x8*)&dst[(size_t)d * Tq + t0 + tc] = v;
    }
}

// ---------- attention with cross-block k-split ----------
// block = (bh, q-tile qi, half). half 0 covers k-tiles [0,(n+1)/2), half 1 [(n+1)/2, n), n=qi+1.
// Writes UNNORMALIZED partial O (bf16) and partial n2 (fp32); combine kernel finishes.
__global__ __launch_bounds__(256)
void attn_kernel(const bf16_t* __restrict__ qkv, const bf16_t* __restrict__ vt,
                 bf16_t* __restrict__ Opart0, bf16_t* __restrict__ Opart1,
                 float* __restrict__ n2part) {
    __shared__ __align__(16) bf16_t Ks[64 * 64];  // swizzled [key][d]
    __shared__ __align__(16) bf16_t Vs[64 * 64];  // swizzled [d][key]
    __shared__ __align__(16) bf16_t Ws[64 * 64];  // swizzled [q][key]

    const int tid = threadIdx.x;
    const int wave = tid >> 6;
    const int lane = tid & 63;
    const int lrow = lane & 15;
    const int lg   = lane >> 4;     // 0..3
    const int er = lg * 4;
    const int ec = lane & 15;

    const int raw  = blockIdx.x;          // 0..63, heavy-first
    const int qi   = 31 - (raw >> 1);
    const int half = raw & 1;
    const int q0   = qi * 64;
    const int bh = blockIdx.y;
    const int b = bh >> 4, h = bh & 15;

    const int n  = qi + 1;
    const int nh = (n + 1) >> 1;
    const int lo = half ? nh : 0;
    const int hi = half ? n  : nh;

    const bf16_t* Qb  = qkv + (size_t)b * Tq * LDQKV + h * HSq;
    const bf16_t* Kb  = Qb + Cq;
    const bf16_t* Vtb = vt + (size_t)bh * HSq * Tq;

    // Q fragments (A-operand layout)
    bf16x8 qf[2];
    {
        const bf16_t* qrow = Qb + (size_t)(q0 + wave * 16 + lrow) * LDQKV + lg * 8;
        qf[0] = *(const bf16x8*)(qrow);
        qf[1] = *(const bf16x8*)(qrow + 32);
    }

    f32x4 oacc[4] = {};
    float n2[4] = {0.f, 0.f, 0.f, 0.f};

    for (int kt = lo; kt < hi; kt++) {
        const int key0 = kt * 64;
        // async swizzled staging: slot s holds chunk (r=s>>3, cg=(s&7)^(r&7))
        #pragma unroll
        for (int i = 0; i < 2; i++) {
            int s = i * 256 + tid;
            int r = s >> 3, cg = (s & 7) ^ (r & 7);
            async_load16(Kb + (size_t)(key0 + r) * LDQKV + cg * 8, &Ks[s * 8]);
            async_load16(Vtb + (size_t)r * Tq + key0 + cg * 8, &Vs[s * 8]);
        }
        __syncthreads();  // drains vmcnt (compiler emits vmcnt(0) before barrier)

        // S = Q K^T
        f32x4 sacc[4] = {};
        #pragma unroll
        for (int j = 0; j < 4; j++) {
            int r = j * 16 + lrow;
            bf16x8 kf0 = *(const bf16x8*)&Ks[SWZ(r, lg)];
            bf16x8 kf1 = *(const bf16x8*)&Ks[SWZ(r, 4 + lg)];
            sacc[j] = MFMA_BF16(qf[0], kf0, sacc[j]);
            sacc[j] = MFMA_BF16(qf[1], kf1, sacc[j]);
        }

        // softplus(0.125*a) = 0.125*max(a,0) + ln2*log2(1+exp2(-0.125*log2e*|a|))
        const bool diag = (kt == qi);  // wave-uniform branch
        #pragma unroll
        for (int j = 0; j < 4; j++) {
            #pragma unroll
            for (int v = 0; v < 4; v++) {
                float a = sacc[j][v];
                float w = 0.125f * fmaxf(a, 0.0f)
                        + 0.69314718f * __builtin_amdgcn_logf(
                              1.0f + __builtin_amdgcn_exp2f(-0.18033688f * fabsf(a)));
                if (diag) {
                    int key = key0 + j * 16 + ec;
                    if (key > q0 + wave * 16 + er + v) w = 0.0f;
                }
                n2[v] += w * w;
                int q = wave * 16 + er + v;
                int col = j * 16 + ec;
                Ws[SWZ(q, col >> 3) + (col & 7)] = (bf16_t)w;
            }
        }

        // O += W V  (Ws written/read by same wave only -> no barrier needed)
        #pragma unroll
        for (int s2 = 0; s2 < 2; s2++) {
            bf16x8 wf = *(const bf16x8*)&Ws[SWZ(wave * 16 + lrow, s2 * 4 + lg)];
            #pragma unroll
            for (int jd = 0; jd < 4; jd++) {
                bf16x8 vf = *(const bf16x8*)&Vs[SWZ(jd * 16 + lrow, s2 * 4 + lg)];
                oacc[jd] = MFMA_BF16(wf, vf, oacc[jd]);
            }
        }
        __syncthreads();
    }

    // reduce n2 across the 16 lanes of each row-group
    #pragma unroll
    for (int v = 0; v < 4; v++) {
        float x = n2[v];
        #pragma unroll
        for (int m = 1; m < 16; m <<= 1) x += __shfl_xor(x, m, 64);
        n2[v] = x;
    }

    // partial epilogue (unconditional: ws is poisoned, zero-iteration halves must write zeros)
    bf16_t* Op = (half ? Opart1 : Opart0) + (size_t)(bh * 32 + qi) * 4096;
    #pragma unroll
    for (int jd = 0; jd < 4; jd++) {
        #pragma unroll
        for (int v = 0; v < 4; v++) {
            Op[(wave * 16 + er + v) * 64 + jd * 16 + ec] = (bf16_t)oacc[jd][v];
        }
    }
    if (ec == 0) {
        float* np = n2part + ((size_t)(half * 1024 + bh * 32 + qi)) * 64 + wave * 16;
        #pragma unroll
        for (int v = 0; v < 4; v++) np[er + v] = n2[v];
    }
}

// ---------- combine partials: ao = (O0+O1) * rsqrt(n20+n21) ----------
__global__ __launch_bounds__(256)
void combine_kernel(const bf16_t* __restrict__ O0, const bf16_t* __restrict__ O1,
                    const float* __restrict__ n2part, bf16_t* __restrict__ ao) {
    const int qi = blockIdx.x;
    const int bh = blockIdx.y;
    const int b = bh >> 4, h = bh & 15;
    const int t = threadIdx.x;
    const size_t base = (size_t)(bh * 32 + qi) * 4096;
    const float* np0 = n2part + (size_t)(bh * 32 + qi) * 64;
    const float* np1 = np0 + (size_t)1024 * 64;
    #pragma unroll
    for (int i = 0; i < 2; i++) {
        int idx = i * 2048 + t * 8;
        int row = idx >> 6, col = idx & 63;
        bf16x8 a = *(const bf16x8*)(O0 + base + idx);
        bf16x8 c = *(const bf16x8*)(O1 + base + idx);
        float inv = rsqrtf(np0[row] + np1[row]);
        bf16x8 o;
        #pragma unroll
        for (int j = 0; j < 8; j++) o[j] = (bf16_t)(((float)a[j] + (float)c[j]) * inv);
        *(bf16x8*)(ao + (size_t)(b * Tq + qi * 64 + row) * Cq + h * HSq + col) = o;
    }
}

// ---------- launch ----------
extern "C" void kernel_launch(void* const* d_in, const int* in_sizes, int n_in,
                              void* d_out, int out_size, void* d_ws, size_t ws_size,
                              hipStream_t stream) {
    const float* x     = (const float*)d_in[0];
    const float* wqkv  = (const float*)d_in[1];
    const float* wproj = (const float*)d_in[2];
    const float* bproj = (const float*)d_in[3];
    float* out = (float*)d_out;

    // workspace layout (64 MB peak; xb/wqkvb regions are reused for partials after gemm1)
    char* ws = (char*)d_ws;
    bf16_t* wprojb = (bf16_t*)(ws);                    //  2 MB [0,2)    cvt -> gemm2
    bf16_t* xb     = (bf16_t*)(ws + ( 2u << 20));      //  8 MB [2,10)   cvt -> gemm1
    bf16_t* wqkvb  = (bf16_t*)(ws + (10u << 20));      //  6 MB [10,16)  cvt -> gemm1
    bf16_t* qkvb   = (bf16_t*)(ws + (16u << 20));      // 24 MB [16,40)
    bf16_t* vtb    = (bf16_t*)(ws + (40u << 20));      //  8 MB [40,48)
    bf16_t* aob    = (bf16_t*)(ws + (48u << 20));      //  8 MB [48,56)
    bf16_t* opart0 = (bf16_t*)(ws + ( 2u << 20));      //  8 MB over dead xb
    float*  n2part = (float*)(ws + (10u << 20));       // 512 KB over dead wqkvb
    bf16_t* opart1 = (bf16_t*)(ws + (56u << 20));      //  8 MB [56,64)

    cvt_f32_bf16<<<1024, 256, 0, stream>>>(wproj, wprojb, Cq * Cq);
    cvt_f32_bf16<<<4096, 256, 0, stream>>>(x, xb, Mrows * Cq);
    cvt_f32_bf16<<<3072, 256, 0, stream>>>(wqkv, wqkvb, 3 * Cq * Cq);

    // QKV projection: [4096,1024] x [3072,1024]^T -> bf16 [4096,3072]
    gemm_bt<0><<<dim3(24, 32), 256, 0, stream>>>(xb, wqkvb, (void*)qkvb, nullptr,
                                                 Mrows, 3 * Cq, Cq);
    // V transpose for PV B-operand
    transpose_v<<<dim3(32, 32), 256, 0, stream>>>(qkvb, vtb);
    // attention (k-split, 2048 blocks) + combine
    attn_kernel<<<dim3(64, 32), 256, 0, stream>>>(qkvb, vtb, opart0, opart1, n2part);
    combine_kernel<<<dim3(32, 32), 256, 0, stream>>>(opart0, opart1, n2part, aob);
    // output projection + bias: [4096,1024] x [1024,1024]^T -> fp32 [4096,1024]
    gemm_bt<1><<<dim3(8, 32), 256, 0, stream>>>(aob, wprojb, (void*)out, bproj,
                                                Mrows, Cq, Cq);
}

// Round 3
// 210.660 us; speedup vs baseline: 1.2742x; 1.1148x over previous
//
#include <hip/hip_runtime.h>
#include <cstdint>
#include <cstddef>

// ---------- types ----------
typedef __bf16 bf16_t;
typedef __bf16 bf16x8 __attribute__((ext_vector_type(8)));
typedef __bf16 bf16x4 __attribute__((ext_vector_type(4)));
typedef float  f32x4  __attribute__((ext_vector_type(4)));

#define MFMA_BF16(a, b, c) __builtin_amdgcn_mfma_f32_16x16x32_bf16((a), (b), (c), 0, 0, 0)

// async global->LDS, 16B per lane. LDS dest must be wave-uniform base + lane*16.
__device__ __forceinline__ void async_load16(const void* g, void* l) {
    __builtin_amdgcn_global_load_lds((const __attribute__((address_space(1))) void*)g,
                                     (__attribute__((address_space(3))) void*)l,
                                     16, 0, 0);
}

// XOR-swizzled LDS layout for a 64x64 bf16 tile stored as 16B chunks (8 chunks/row).
// chunk (r, cg) lives at slot r*8 + (cg ^ (r&7)); returns bf16 element offset.
#define SWZ(r, cg) ((((r) << 3) | ((cg) ^ ((r) & 7))) << 3)

// ---------- problem constants ----------
#define Bq   2
#define Tq   2048
#define Cq   1024
#define Hq   16
#define HSq  64
#define LDQKV 3072   // 3*C
#define Mrows 4096   // B*T

// ---------- fp32 -> bf16 convert ----------
__global__ void cvt_f32_bf16(const float* __restrict__ in, bf16_t* __restrict__ out, int n) {
    int i = (blockIdx.x * blockDim.x + threadIdx.x) * 4;
    if (i + 3 < n) {
        float4 v = *(const float4*)(in + i);
        bf16x4 o;
        o[0] = (bf16_t)v.x; o[1] = (bf16_t)v.y; o[2] = (bf16_t)v.z; o[3] = (bf16_t)v.w;
        *(bf16x4*)(out + i) = o;
    }
}

// ---------- GEMM: C[m][n] = sum_k A[m][k]*B[n][k] (+bias), A:[M,K], B:[N,K] row-major ----------
// BMx128 tile, BK=32, 256 threads = 4 waves (2x2), per wave (BM/2)x64 via 16x16x32 MFMA.
template <int BM, int OUT_FP32>
__global__ __launch_bounds__(256)
void gemm_bt(const bf16_t* __restrict__ A, const bf16_t* __restrict__ B,
             void* __restrict__ Cout, const float* __restrict__ bias,
             int M, int N, int K) {
    constexpr int MR = BM / 32;   // MFMA row-tiles per wave
    __shared__ __align__(16) bf16_t As[BM * 32];
    __shared__ __align__(16) bf16_t Bs[128 * 32];

    const int tid  = threadIdx.x;
    const int wave = tid >> 6;
    const int lane = tid & 63;
    const int m0 = blockIdx.y * BM;
    const int n0 = blockIdx.x * 128;
    const int wm = (wave >> 1) * (BM / 2);
    const int wn = (wave & 1) * 64;
    const int lrow = lane & 15;
    const int lko  = (lane >> 4) * 8;

    f32x4 acc[MR][4] = {};

    const bf16_t* Ag = A + (size_t)m0 * K;
    const bf16_t* Bg = B + (size_t)n0 * K;
    const int c0 = tid, c1 = tid + 256;

    for (int k0 = 0; k0 < K; k0 += 32) {
        async_load16(Ag + (size_t)(c0 >> 2) * K + k0 + (c0 & 3) * 8, &As[c0 * 8]);
        if (BM == 128)
            async_load16(Ag + (size_t)(c1 >> 2) * K + k0 + (c1 & 3) * 8, &As[c1 * 8]);
        async_load16(Bg + (size_t)(c0 >> 2) * K + k0 + (c0 & 3) * 8, &Bs[c0 * 8]);
        async_load16(Bg + (size_t)(c1 >> 2) * K + k0 + (c1 & 3) * 8, &Bs[c1 * 8]);
        __syncthreads();

        bf16x8 af[MR], bfr[4];
        #pragma unroll
        for (int r = 0; r < MR; r++) af[r] = *(const bf16x8*)&As[(wm + r * 16 + lrow) * 32 + lko];
        #pragma unroll
        for (int c = 0; c < 4; c++) bfr[c] = *(const bf16x8*)&Bs[(wn + c * 16 + lrow) * 32 + lko];
        #pragma unroll
        for (int r = 0; r < MR; r++)
            #pragma unroll
            for (int c = 0; c < 4; c++)
                acc[r][c] = MFMA_BF16(af[r], bfr[c], acc[r][c]);
        __syncthreads();
    }

    const int er = (lane >> 4) * 4;
    const int ec = lane & 15;
    #pragma unroll
    for (int r = 0; r < MR; r++) {
        #pragma unroll
        for (int c = 0; c < 4; c++) {
            int m = m0 + wm + r * 16 + er;
            int n = n0 + wn + c * 16 + ec;
            #pragma unroll
            for (int v = 0; v < 4; v++) {
                if (OUT_FP32) {
                    ((float*)Cout)[(size_t)(m + v) * N + n] = acc[r][c][v] + bias[n];
                } else {
                    ((bf16_t*)Cout)[(size_t)(m + v) * N + n] = (bf16_t)acc[r][c][v];
                }
            }
        }
    }
}

// ---------- V transpose: Vt[b][h][d][t] = QKV[b*T+t][2C + h*64 + d] ----------
__global__ __launch_bounds__(256)
void transpose_v(const bf16_t* __restrict__ qkv, bf16_t* __restrict__ vt) {
    __shared__ __align__(16) bf16_t Ls[64 * 72];
    const int tid = threadIdx.x;
    const int t0 = blockIdx.x * 64;
    const int bh = blockIdx.y;
    const int b = bh >> 4, h = bh & 15;
    const bf16_t* src = qkv + (size_t)b * Tq * LDQKV + 2 * Cq + h * HSq;
    #pragma unroll
    for (int i = 0; i < 2; i++) {
        int c = i * 256 + tid;
        int tl = c >> 3, dc = (c & 7) * 8;
        bf16x8 v = *(const bf16x8*)(src + (size_t)(t0 + tl) * LDQKV + dc);
        *(bf16x8*)&Ls[tl * 72 + dc] = v;
    }
    __syncthreads();
    bf16_t* dst = vt + (size_t)bh * HSq * Tq;
    #pragma unroll
    for (int i = 0; i < 2; i++) {
        int c = i * 256 + tid;
        int d = c >> 3, tc = (c & 7) * 8;
        bf16x8 v;
        #pragma unroll
        for (int j = 0; j < 8; j++) v[j] = Ls[(tc + j) * 72 + d];
        *(bf16x8*)&dst[(size_t)d * Tq + t0 + tc] = v;
    }
}

// ---------- attention with cross-block k-split, S^T formulation ----------
// block = (bh, q-tile qi, half). Computes S^T = K Q^T so W-tile writes pack to b64.
// Softplus in log2 domain (global scale cancels in O/||w||).
// Register double-buffering: global->VGPR prefetch in flight during compute.
__global__ __launch_bounds__(256)
void attn_kernel(const bf16_t* __restrict__ qkv, const bf16_t* __restrict__ vt,
                 bf16_t* __restrict__ Opart0, bf16_t* __restrict__ Opart1,
                 float* __restrict__ n2part) {
    __shared__ __align__(16) bf16_t Ks[64 * 64];  // swizzled [key][d]
    __shared__ __align__(16) bf16_t Vs[64 * 64];  // swizzled [d][key]
    __shared__ __align__(16) bf16_t Ws[64 * 64];  // swizzled [q][key]

    const int tid = threadIdx.x;
    const int wave = tid >> 6;
    const int lane = tid & 63;
    const int lrow = lane & 15;
    const int lg   = lane >> 4;     // 0..3
    const int er = lg * 4;
    const int ec = lane & 15;

    const int raw  = blockIdx.x;          // 0..63, heavy-first
    const int qi   = 31 - (raw >> 1);
    const int half = raw & 1;
    const int q0   = qi * 64;
    const int bh = blockIdx.y;
    const int b = bh >> 4, h = bh & 15;

    const int n  = qi + 1;
    const int nh = (n + 1) >> 1;
    const int lo = half ? nh : 0;
    const int hi = half ? n  : nh;

    const bf16_t* Qb  = qkv + (size_t)b * Tq * LDQKV + h * HSq;
    const bf16_t* Kb  = Qb + Cq;
    const bf16_t* Vtb = vt + (size_t)bh * HSq * Tq;

    // Q fragments (B-operand now; same lane mapping as A)
    bf16x8 qf[2];
    {
        const bf16_t* qrow = Qb + (size_t)(q0 + wave * 16 + lrow) * LDQKV + lg * 8;
        qf[0] = *(const bf16x8*)(qrow);
        qf[1] = *(const bf16x8*)(qrow + 32);
    }

    // staging slots (swizzled): thread covers slots tid and tid+256
    const int s0 = tid, s1 = tid + 256;
    const int r0 = s0 >> 3, cg0 = (s0 & 7) ^ (r0 & 7);
    const int r1 = s1 >> 3, cg1 = (s1 & 7) ^ (r1 & 7);
    const bf16_t* kp0 = Kb + (size_t)r0 * LDQKV + cg0 * 8;
    const bf16_t* kp1 = Kb + (size_t)r1 * LDQKV + cg1 * 8;
    const bf16_t* vp0 = Vtb + (size_t)r0 * Tq + cg0 * 8;
    const bf16_t* vp1 = Vtb + (size_t)r1 * Tq + cg1 * 8;

    bf16x8 kreg0, kreg1, vreg0, vreg1;
    if (lo < hi) {
        const size_t key0 = (size_t)lo * 64;
        kreg0 = *(const bf16x8*)(kp0 + key0 * LDQKV);
        kreg1 = *(const bf16x8*)(kp1 + key0 * LDQKV);
        vreg0 = *(const bf16x8*)(vp0 + key0);
        vreg1 = *(const bf16x8*)(vp1 + key0);
    }

    f32x4 oacc[4] = {};
    float n2 = 0.f;
    const float C1 = 0.18033688f;  // 0.125 * log2(e)

    for (int kt = lo; kt < hi; kt++) {
        __syncthreads();  // all waves done reading LDS from previous iteration
        *(bf16x8*)&Ks[s0 * 8] = kreg0;   // compiler waits vmcnt on the prefetch here
        *(bf16x8*)&Ks[s1 * 8] = kreg1;
        *(bf16x8*)&Vs[s0 * 8] = vreg0;
        *(bf16x8*)&Vs[s1 * 8] = vreg1;
        __syncthreads();

        if (kt + 1 < hi) {  // prefetch next tile; in flight during compute below
            const size_t key0 = (size_t)(kt + 1) * 64;
            kreg0 = *(const bf16x8*)(kp0 + key0 * LDQKV);
            kreg1 = *(const bf16x8*)(kp1 + key0 * LDQKV);
            vreg0 = *(const bf16x8*)(vp0 + key0);
            vreg1 = *(const bf16x8*)(vp1 + key0);
        }

        // S^T = K Q^T : C-layout gives lane 4 consecutive KEYS (rows) for one q (col)
        f32x4 sacc[4];
        #pragma unroll
        for (int j = 0; j < 4; j++) {
            int r = j * 16 + lrow;
            bf16x8 kf0 = *(const bf16x8*)&Ks[SWZ(r, lg)];
            bf16x8 kf1 = *(const bf16x8*)&Ks[SWZ(r, 4 + lg)];
            f32x4 z = {};
            z = MFMA_BF16(kf0, qf[0], z);
            sacc[j] = MFMA_BF16(kf1, qf[1], z);
        }

        // softplus in log2 domain: w' = max(t,0) + log2(1 + 2^-|t|), t = s*0.125*log2e
        const bool diag = (kt == qi);  // wave-uniform branch
        #pragma unroll
        for (int j = 0; j < 4; j++) {
            bf16x4 wb;
            #pragma unroll
            for (int v = 0; v < 4; v++) {
                float t = sacc[j][v] * C1;
                float e = __builtin_amdgcn_exp2f(-fabsf(t));
                float w = fmaxf(t, 0.f) + __builtin_amdgcn_logf(1.f + e);  // v_log = log2
                if (diag && (j * 16 + er + v > wave * 16 + ec)) w = 0.f;   // key > q
                n2 += w * w;
                wb[v] = (bf16_t)w;
            }
            // 4 consecutive keys, one q: packed b64 write
            *(bf16x4*)&Ws[SWZ(wave * 16 + ec, 2 * j + (lg >> 1)) + (lg & 1) * 4] = wb;
        }

        // O += W V  (Ws written/read by same wave only -> DS pipe in-order, no barrier)
        #pragma unroll
        for (int s2 = 0; s2 < 2; s2++) {
            bf16x8 wf = *(const bf16x8*)&Ws[SWZ(wave * 16 + lrow, s2 * 4 + lg)];
            #pragma unroll
            for (int jd = 0; jd < 4; jd++) {
                bf16x8 vf = *(const bf16x8*)&Vs[SWZ(jd * 16 + lrow, s2 * 4 + lg)];
                oacc[jd] = MFMA_BF16(wf, vf, oacc[jd]);
            }
        }
    }

    // n2 lives per lane for q = wave*16+ec; reduce over the 4 lane-groups
    n2 += __shfl_xor(n2, 16, 64);
    n2 += __shfl_xor(n2, 32, 64);

    // partial epilogue (unconditional: zero-iteration halves must write zeros)
    bf16_t* Op = (half ? Opart1 : Opart0) + (size_t)(bh * 32 + qi) * 4096;
    #pragma unroll
    for (int jd = 0; jd < 4; jd++) {
        #pragma unroll
        for (int v = 0; v < 4; v++) {
            Op[(wave * 16 + er + v) * 64 + jd * 16 + ec] = (bf16_t)oacc[jd][v];
        }
    }
    if (lg == 0) {
        n2part[((size_t)(half * 1024 + bh * 32 + qi)) * 64 + wave * 16 + ec] = n2;
    }
}

// ---------- combine partials: ao = (O0+O1) * rsqrt(n20+n21) ----------
__global__ __launch_bounds__(256)
void combine_kernel(const bf16_t* __restrict__ O0, const bf16_t* __restrict__ O1,
                    const float* __restrict__ n2part, bf16_t* __restrict__ ao) {
    const int qi = blockIdx.x;
    const int bh = blockIdx.y;
    const int b = bh >> 4, h = bh & 15;
    const int t = threadIdx.x;
    const size_t base = (size_t)(bh * 32 + qi) * 4096;
    const float* np0 = n2part + (size_t)(bh * 32 + qi) * 64;
    const float* np1 = np0 + (size_t)1024 * 64;
    #pragma unroll
    for (int i = 0; i < 2; i++) {
        int idx = i * 2048 + t * 8;
        int row = idx >> 6, col = idx & 63;
        bf16x8 a = *(const bf16x8*)(O0 + base + idx);
        bf16x8 c = *(const bf16x8*)(O1 + base + idx);
        float inv = rsqrtf(np0[row] + np1[row]);
        bf16x8 o;
        #pragma unroll
        for (int j = 0; j < 8; j++) o[j] = (bf16_t)(((float)a[j] + (float)c[j]) * inv);
        *(bf16x8*)(ao + (size_t)(b * Tq + qi * 64 + row) * Cq + h * HSq + col) = o;
    }
}

// ---------- launch ----------
extern "C" void kernel_launch(void* const* d_in, const int* in_sizes, int n_in,
                              void* d_out, int out_size, void* d_ws, size_t ws_size,
                              hipStream_t stream) {
    const float* x     = (const float*)d_in[0];
    const float* wqkv  = (const float*)d_in[1];
    const float* wproj = (const float*)d_in[2];
    const float* bproj = (const float*)d_in[3];
    float* out = (float*)d_out;

    // workspace layout (64 MB peak; xb/wqkvb regions are reused for partials after gemm1)
    char* ws = (char*)d_ws;
    bf16_t* wprojb = (bf16_t*)(ws);                    //  2 MB [0,2)    cvt -> gemm2
    bf16_t* xb     = (bf16_t*)(ws + ( 2u << 20));      //  8 MB [2,10)   cvt -> gemm1
    bf16_t* wqkvb  = (bf16_t*)(ws + (10u << 20));      //  6 MB [10,16)  cvt -> gemm1
    bf16_t* qkvb   = (bf16_t*)(ws + (16u << 20));      // 24 MB [16,40)
    bf16_t* vtb    = (bf16_t*)(ws + (40u << 20));      //  8 MB [40,48)
    bf16_t* aob    = (bf16_t*)(ws + (48u << 20));      //  8 MB [48,56)
    bf16_t* opart0 = (bf16_t*)(ws + ( 2u << 20));      //  8 MB over dead xb
    float*  n2part = (float*)(ws + (10u << 20));       // 512 KB over dead wqkvb
    bf16_t* opart1 = (bf16_t*)(ws + (56u << 20));      //  8 MB [56,64)

    cvt_f32_bf16<<<1024, 256, 0, stream>>>(wproj, wprojb, Cq * Cq);
    cvt_f32_bf16<<<4096, 256, 0, stream>>>(x, xb, Mrows * Cq);
    cvt_f32_bf16<<<3072, 256, 0, stream>>>(wqkv, wqkvb, 3 * Cq * Cq);

    // QKV projection: [4096,1024] x [3072,1024]^T -> bf16 [4096,3072]
    gemm_bt<128, 0><<<dim3(24, 32), 256, 0, stream>>>(xb, wqkvb, (void*)qkvb, nullptr,
                                                      Mrows, 3 * Cq, Cq);
    // V transpose for PV B-operand
    transpose_v<<<dim3(32, 32), 256, 0, stream>>>(qkvb, vtb);
    // attention (k-split, 2048 blocks) + combine
    attn_kernel<<<dim3(64, 32), 256, 0, stream>>>(qkvb, vtb, opart0, opart1, n2part);
    combine_kernel<<<dim3(32, 32), 256, 0, stream>>>(opart0, opart1, n2part, aob);
    // output projection + bias: [4096,1024] x [1024,1024]^T -> fp32 [4096,1024]
    // BM=64 tile: 512 blocks (2/CU) instead of 256 (1/CU)
    gemm_bt<64, 1><<<dim3(8, 64), 256, 0, stream>>>(aob, wprojb, (void*)out, bproj,
                                                    Mrows, Cq, Cq);
}